// Round 6
// baseline (560.379 us; speedup 1.0000x reference)
//
#include <hip/hip_runtime.h>

// Problem constants (from reference)
constexpr int N_NODES = 100000;
constexpr int N_EDGES = 1000000;
constexpr int D_NODE  = 64;
constexpr int D_EDGE  = 32;
constexpr int D_GLOB  = 32;
constexpr int OUT_DIM = 64;
constexpr int K1 = 2*D_NODE + D_EDGE + D_GLOB; // 192
constexpr int K2 = D_NODE + OUT_DIM + D_GLOB;  // 160

typedef _Float16 f16x8 __attribute__((ext_vector_type(8)));
typedef unsigned short ushort8_t __attribute__((ext_vector_type(8)));
typedef float floatx16 __attribute__((ext_vector_type(16)));

// LDS feature-tile row stride (f16 elems): 400 B rows, 16B-aligned.
constexpr int FS = 200;

// d_ws layout (bytes), all 16B-aligned (end = 17894656, same as R3's proven fit):
//   [0,        24576)     W1t f16 [64][192]  (transposed: [n][k])
//   [24576,    45056)     W2t f16 [64][160]
//   [45056,    46080)     ub  f16 [16][32]
//   [46080,    12846080)  xb  f16 [100000][64]   (12.8 MB)
//   [12846080, 13370368)  cnt int[131072]  (hist; ints [130048..130175] reused as bsum —
//                         corruption from that reuse only propagates to indices >=100000, unused)
//   [13370368, 13894656)  cursor int[131072] (scanned starts, consumed by scatter)
//   [13894656, 17894656)  sorted_e int[1000000] (edge ids sorted by dst)
// agg (f16 [100000][64]) lives INSIDE d_out: row n = first 128 B of out row n.
constexpr size_t WS_W1T  = 0;
constexpr size_t WS_W2T  = 24576;
constexpr size_t WS_UB   = 45056;
constexpr size_t WS_XB   = 46080;
constexpr size_t WS_CNT  = 12846080;
constexpr size_t WS_CUR  = 13370368;
constexpr size_t WS_SORT = 13894656;
constexpr int BSUM_BASE  = 130048;   // int index inside cnt region

__device__ inline unsigned pack_f2(float a, float b) {
    auto h = __builtin_amdgcn_cvt_pkrtz(a, b);    // v_cvt_pkrtz_f16_f32
    return __builtin_bit_cast(unsigned, h);
}

// ---------------------------------------------------------------------------
// Prep: f16-convert x, u; f16+transpose W1, W2; dst histogram (cnt pre-zeroed).
// ---------------------------------------------------------------------------
__global__ __launch_bounds__(256) void prep_kernel(
    const float* __restrict__ x, const float* __restrict__ u,
    const float* __restrict__ W1, const float* __restrict__ W2,
    const int* __restrict__ ei, int* __restrict__ cnt,
    unsigned short* __restrict__ ws_w1t, unsigned short* __restrict__ ws_w2t,
    unsigned short* __restrict__ ws_ub, unsigned short* __restrict__ ws_xb)
{
    const int t = blockIdx.x * 256 + threadIdx.x;
    const int stride = gridDim.x * 256;
    const float4* x4 = (const float4*)x;
    for (int i = t; i < N_NODES * 16; i += stride) {       // x: 1.6M float4
        float4 v = x4[i];
        uint2 pk;
        pk.x = pack_f2(v.x, v.y);
        pk.y = pack_f2(v.z, v.w);
        *(uint2*)&ws_xb[i * 4] = pk;
    }
    for (int i = t; i < N_EDGES; i += stride)              // dst histogram
        atomicAdd(&cnt[ei[N_EDGES + i]], 1);
    for (int i = t; i < K1 * 64; i += stride) {            // W1 [k][n] -> [n][k]
        int k = i >> 6, n = i & 63;
        _Float16 h = (_Float16)W1[i];
        ws_w1t[n * K1 + k] = __builtin_bit_cast(unsigned short, h);
    }
    for (int i = t; i < K2 * 64; i += stride) {            // W2 [k][n] -> [n][k]
        int k = i >> 6, n = i & 63;
        _Float16 h = (_Float16)W2[i];
        ws_w2t[n * K2 + k] = __builtin_bit_cast(unsigned short, h);
    }
    for (int i = t; i < 16 * D_GLOB; i += stride) {        // u
        _Float16 h = (_Float16)u[i];
        ws_ub[i] = __builtin_bit_cast(unsigned short, h);
    }
}

// ---------------------------------------------------------------------------
// scan_a: 128 blocks x 256 thr; block b scans cnt ints [b*1024, b*1024+1024)
// (int4/thread) into block-local exclusive prefixes written to cursor[];
// block total -> bsum[b] (= cnt[BSUM_BASE+b]; safe, see layout note).
// ---------------------------------------------------------------------------
__global__ __launch_bounds__(256) void scan_a_kernel(
    const int* __restrict__ cnt, int* __restrict__ cursor, int* __restrict__ bsum)
{
    __shared__ int l[256];
    const int t = threadIdx.x;
    const int idx = blockIdx.x * 256 + t;
    int4 v = ((const int4*)cnt)[idx];
    int s = v.x + v.y + v.z + v.w;
    l[t] = s;
    __syncthreads();
    for (int off = 1; off < 256; off <<= 1) {
        int a = (t >= off) ? l[t - off] : 0;
        __syncthreads();
        l[t] += a;
        __syncthreads();
    }
    int ex = l[t] - s;                        // exclusive prefix within block
    int4 o;
    o.x = ex; o.y = ex + v.x; o.z = o.y + v.y; o.w = o.z + v.z;
    ((int4*)cursor)[idx] = o;
    if (t == 255) bsum[blockIdx.x] = l[255];
}

// ---------------------------------------------------------------------------
// scan_c: 128 blocks; each adds the prefix of bsum[0..b) to its cursor chunk.
// ---------------------------------------------------------------------------
__global__ __launch_bounds__(256) void scan_c_kernel(
    const int* __restrict__ bsum, int* __restrict__ cursor)
{
    __shared__ int sb[128];
    __shared__ int soff;
    const int t = threadIdx.x;
    if (t < 128) sb[t] = bsum[t];
    __syncthreads();
    if (t == 0) {
        int s = 0;
        for (int i = 0; i < (int)blockIdx.x; ++i) s += sb[i];
        soff = s;
    }
    __syncthreads();
    const int idx = blockIdx.x * 256 + t;
    int4 v = ((const int4*)cursor)[idx];
    v.x += soff; v.y += soff; v.z += soff; v.w += soff;
    ((int4*)cursor)[idx] = v;
}

// ---------------------------------------------------------------------------
// Scatter: place edge ids into dst-sorted order via cursor atomics.
// ---------------------------------------------------------------------------
__global__ __launch_bounds__(256) void scatter_kernel(
    const int* __restrict__ ei, int* __restrict__ cursor,
    int* __restrict__ sorted_e)
{
    const int t = blockIdx.x * 256 + threadIdx.x;
    const int stride = gridDim.x * 256;
    for (int e = t; e < N_EDGES; e += stride) {
        int d = ei[N_EDGES + e];
        int pos = atomicAdd(&cursor[d], 1);
        sorted_e[pos] = e;
    }
}

// ---------------------------------------------------------------------------
// Edge kernel over SORTED edges (32x32x16 MFMA): msg = relu(feat @ W1 + b1),
// D[edge][ch]. Chunk = 64 consecutive sorted edges (~7 distinct dsts).
// Epilogue: stage msg f32 in LDS, then segmented serial reduce (32 ch-pairs x
// 4 groups of 16 edges, f32 accumulation, flush on dst change) -> ~330
// pk_add_f16 per block instead of 2048 (6x fewer TCC atomic slots).
// agg f16 row d sits at byte offset d*256 of d_out (pre-zeroed).
// ---------------------------------------------------------------------------
__global__ __launch_bounds__(256, 6) void edge_kernel(
    const unsigned short* __restrict__ xb, const int* __restrict__ ei,
    const float* __restrict__ ea, const unsigned short* __restrict__ ub,
    const int* __restrict__ batch, const int* __restrict__ sorted_e,
    const unsigned short* __restrict__ W1t,
    const float* __restrict__ b1, float* __restrict__ out)
{
    __shared__ __align__(16) unsigned short smem[64 * FS]; // 25600 B (feat, then f32 msg[64][64])
    __shared__ int s_e[64];
    __shared__ int s_dst[64];
    __shared__ int s_src[64];
    __shared__ int s_b[64];

    const int tid  = threadIdx.x;
    const int lane = tid & 63;
    const int wv   = tid >> 6;
    const int tile = blockIdx.x;
    const int eh   = wv >> 1;
    const int nh   = wv & 1;
    const int col  = lane & 31;
    const int half = lane >> 5;
    const float4* ea4 = (const float4*)ea;

    if (tid < 64) {
        int e = sorted_e[tile * 64 + tid];
        int d = ei[N_EDGES + e];            // dst = edge_index[1]
        s_e[tid]   = e;
        s_dst[tid] = d;
        s_src[tid] = ei[e];                 // src = edge_index[0]
        s_b[tid]   = batch[d];
    }

    // B fragments: B[k][n], n = nh*32+col, k = s*16 + half*8 + j
    f16x8 Wf[12];
    #pragma unroll
    for (int s = 0; s < 12; ++s)
        Wf[s] = __builtin_bit_cast(f16x8,
            *(const ushort8_t*)&W1t[(nh*32 + col) * K1 + s*16 + half*8]);

    // Channel-pair for the reduce phase: (tid&31)*2 == (lane&31)*2
    const int chp = (lane & 31) * 2;
    const float2 bv = *(const float2*)&b1[chp];

    __syncthreads();                        // indices visible

    // Gather: 64 edges x 24 16B-chunks (x[dst]:8 | x[src]:8 | ea:4 | u:4)
    for (int q = tid; q < 64 * 24; q += 256) {
        int el = q / 24;
        int c  = q - el * 24;
        uint4 pk;
        if (c < 8)       pk = *(const uint4*)&xb[(size_t)s_dst[el] * 64 + c * 8];
        else if (c < 16) pk = *(const uint4*)&xb[(size_t)s_src[el] * 64 + (c - 8) * 8];
        else if (c < 20) {
            float4 v0 = ea4[(size_t)s_e[el] * 8 + (c - 16) * 2 + 0];
            float4 v1 = ea4[(size_t)s_e[el] * 8 + (c - 16) * 2 + 1];
            pk.x = pack_f2(v0.x, v0.y); pk.y = pack_f2(v0.z, v0.w);
            pk.z = pack_f2(v1.x, v1.y); pk.w = pack_f2(v1.z, v1.w);
        } else           pk = *(const uint4*)&ub[s_b[el] * 32 + (c - 20) * 8];
        *(uint4*)&smem[el * FS + c * 8] = pk;
    }
    __syncthreads();                        // feat visible

    // Compute: A rows = edges (eh*32 + col), B cols = channels -> D[edge][ch]
    floatx16 acc = {0,0,0,0,0,0,0,0,0,0,0,0,0,0,0,0};
    #pragma unroll
    for (int s = 0; s < 12; ++s) {
        f16x8 a = __builtin_bit_cast(f16x8,
            *(const ushort8_t*)&smem[(eh*32 + col) * FS + s*16 + half*8]);
        acc = __builtin_amdgcn_mfma_f32_32x32x16_f16(a, Wf[s], acc, 0, 0, 0);
    }

    // Stage msg tile to LDS (f32 [64 edge][64 ch]); C layout:
    // edge = eh*32 + (r&3)+8*(r>>2)+4*half, ch = nh*32+col.
    __syncthreads();                       // all waves done reading feat tile
    float* smemf = (float*)smem;
    #pragma unroll
    for (int r = 0; r < 16; ++r) {
        int e = eh*32 + (r & 3) + 8*(r >> 2) + 4*half;
        smemf[e * 64 + nh*32 + col] = acc[r];
    }
    __syncthreads();

    // Segmented reduce: thread (p = tid&31, g = tid>>5 < 4) scans 16 sorted
    // edges for channel pair chp, f32-accumulating relu(msg+b1); flush one
    // pk_add_f16 per dst-run (avg ~2.6 flushes per 16 edges).
    if (tid < 128) {
        const int g = tid >> 5;
        float r0 = 0.f, r1 = 0.f;
        int cur = s_dst[g * 16];
        for (int j = 0; j < 16; ++j) {
            int ee = g * 16 + j;
            int d = s_dst[ee];
            if (d != cur) {
                unsigned pk = pack_f2(r0, r1);
                unsigned short* p = (unsigned short*)out + (size_t)cur * 128 + chp;
                asm volatile("global_atomic_pk_add_f16 %0, %1, off"
                             :: "v"(p), "v"(pk) : "memory");
                r0 = 0.f; r1 = 0.f; cur = d;
            }
            float2 m = *(const float2*)&smemf[ee * 64 + chp];
            float v0 = m.x + bv.x; r0 += (v0 > 0.f ? v0 : 0.f);
            float v1 = m.y + bv.y; r1 += (v1 > 0.f ? v1 : 0.f);
        }
        unsigned pk = pack_f2(r0, r1);
        unsigned short* p = (unsigned short*)out + (size_t)cur * 128 + chp;
        asm volatile("global_atomic_pk_add_f16 %0, %1, off"
                     :: "v"(p), "v"(pk) : "memory");
    }
}

// ---------------------------------------------------------------------------
// Node kernel (32x32x16 MFMA): out = relu([x, agg, u[batch]] @ W2 + b2)
// agg read f16 from the first 128 B of each out row; in-place, row-exclusive
// per block. One 64-node tile per block (tail guarded).
// ---------------------------------------------------------------------------
__global__ __launch_bounds__(256, 6) void node_kernel(
    const unsigned short* __restrict__ xb, const unsigned short* __restrict__ ub,
    const int* __restrict__ batch, const unsigned short* __restrict__ W2t,
    const float* __restrict__ b2, float* __restrict__ out)
{
    __shared__ __align__(16) unsigned short smem[64 * FS];
    __shared__ int s_b[64];

    const int tid  = threadIdx.x;
    const int lane = tid & 63;
    const int wv   = tid >> 6;
    const int base = blockIdx.x * 64;
    const int eh   = wv >> 1;
    const int nh   = wv & 1;
    const int col  = lane & 31;
    const int half = lane >> 5;

    if (tid < 64) {
        int n = base + tid;
        s_b[tid] = (n < N_NODES) ? batch[n] : 0;
    }

    f16x8 Bf[10];
    #pragma unroll
    for (int s = 0; s < 10; ++s)
        Bf[s] = __builtin_bit_cast(f16x8,
            *(const ushort8_t*)&W2t[(nh*32 + col) * K2 + s*16 + half*8]);
    const float b2v = b2[nh*32 + col];

    __syncthreads();

    // Gather: 64 nodes x 20 16B-chunks (x:8 | agg:8 | u:4)
    const unsigned short* aggb = (const unsigned short*)out;
    for (int q = tid; q < 64 * 20; q += 256) {
        int nl = q / 20;
        int c  = q - nl * 20;
        int n  = base + nl;
        uint4 pk;
        if (n >= N_NODES) pk = uint4{0, 0, 0, 0};
        else if (c < 8)   pk = *(const uint4*)&xb[(size_t)n * 64 + c * 8];
        else if (c < 16)  pk = *(const uint4*)&aggb[(size_t)n * 128 + (c - 8) * 8];
        else              pk = *(const uint4*)&ub[s_b[nl] * 32 + (c - 16) * 8];
        *(uint4*)&smem[nl * FS + c * 8] = pk;
    }
    __syncthreads();

    floatx16 acc = {0,0,0,0,0,0,0,0,0,0,0,0,0,0,0,0};
    #pragma unroll
    for (int s = 0; s < 10; ++s) {
        f16x8 a = __builtin_bit_cast(f16x8,
            *(const ushort8_t*)&smem[(eh*32 + col) * FS + s*16 + half*8]);
        acc = __builtin_amdgcn_mfma_f32_32x32x16_f16(a, Bf[s], acc, 0, 0, 0);
    }

    #pragma unroll
    for (int r = 0; r < 16; ++r) {
        int n = base + eh*32 + (r & 3) + 8*(r >> 2) + 4*half;
        if (n < N_NODES) {
            float vv = acc[r] + b2v;
            out[(size_t)n * 64 + nh*32 + col] = vv > 0.f ? vv : 0.f;
        }
    }
}

extern "C" void kernel_launch(void* const* d_in, const int* in_sizes, int n_in,
                              void* d_out, int out_size, void* d_ws, size_t ws_size,
                              hipStream_t stream) {
    const float* x     = (const float*)d_in[0];
    const int*   ei    = (const int*)d_in[1];
    const float* ea    = (const float*)d_in[2];
    const float* u     = (const float*)d_in[3];
    const int*   batch = (const int*)d_in[4];
    const float* W1    = (const float*)d_in[5];
    const float* b1    = (const float*)d_in[6];
    const float* W2    = (const float*)d_in[7];
    const float* b2    = (const float*)d_in[8];
    float* out = (float*)d_out;

    unsigned short* ws_w1t = (unsigned short*)((char*)d_ws + WS_W1T);
    unsigned short* ws_w2t = (unsigned short*)((char*)d_ws + WS_W2T);
    unsigned short* ws_ub  = (unsigned short*)((char*)d_ws + WS_UB);
    unsigned short* ws_xb  = (unsigned short*)((char*)d_ws + WS_XB);
    int* cnt    = (int*)((char*)d_ws + WS_CNT);
    int* cursor = (int*)((char*)d_ws + WS_CUR);
    int* sorted = (int*)((char*)d_ws + WS_SORT);
    int* bsum   = cnt + BSUM_BASE;

    // agg (f16) accumulates in the low half of each d_out row; zero it all.
    (void)hipMemsetAsync(out, 0, (size_t)out_size * sizeof(float), stream);
    // zero histogram region (padded to 131072 ints; padding also covers bsum)
    (void)hipMemsetAsync(cnt, 0, 524288, stream);

    prep_kernel<<<2048, 256, 0, stream>>>(x, u, W1, W2, ei, cnt,
                                          ws_w1t, ws_w2t, ws_ub, ws_xb);
    scan_a_kernel<<<128, 256, 0, stream>>>(cnt, cursor, bsum);
    scan_c_kernel<<<128, 256, 0, stream>>>(bsum, cursor);
    scatter_kernel<<<2048, 256, 0, stream>>>(ei, cursor, sorted);
    edge_kernel<<<N_EDGES / 64, 256, 0, stream>>>(ws_xb, ei, ea, ws_ub, batch,
                                                  sorted, ws_w1t, b1, out);
    node_kernel<<<(N_NODES + 63) / 64, 256, 0, stream>>>(ws_xb, ws_ub, batch,
                                                         ws_w2t, b2, out);
}